// Round 1
// baseline (8661.898 us; speedup 1.0000x reference)
//
#include <hip/hip_runtime.h>

// Problem constants (fixed by setup_inputs)
static constexpr int NN   = 100000;    // nodes
static constexpr int EE   = 2560000;   // edges
static constexpr int RR   = 8;         // relations
static constexpr int BB   = 8;         // bases
static constexpr int EPER = EE / RR;   // 320000 edges per relation

// ---------------------------------------------------------------------------
// K0: w[r][i][o] = sum_b att[r][b] * basis[b][i][o]   for both layers
// grid = 16 blocks (0..7 -> layer0 rel r, 8..15 -> layer1), block = 1024
// ---------------------------------------------------------------------------
__global__ __launch_bounds__(1024) void compute_w_kernel(
    const float* __restrict__ basis0, const float* __restrict__ att0,
    const float* __restrict__ basis1, const float* __restrict__ att1,
    float* __restrict__ w0, float* __restrict__ w1)
{
    const int r = blockIdx.x & 7;
    const bool l0 = blockIdx.x < 8;
    const float* basis = l0 ? basis0 : basis1;
    const float* att   = l0 ? att0   : att1;
    float*       w     = l0 ? w0     : w1;
    const int io = threadIdx.x;           // i*32 + o, 0..1023
    float acc = 0.f;
#pragma unroll
    for (int b = 0; b < BB; ++b)
        acc += att[r * BB + b] * basis[b * 1024 + io];
    w[r * 1024 + io] = acc;
}

// ---------------------------------------------------------------------------
// K1: xw[slot][n][o] = sum_i x[n][i] * w[r][i][o],  r = r_begin + blockIdx.y
// grid = (ceil(N/32), n_slots), block = 256
// ---------------------------------------------------------------------------
__global__ __launch_bounds__(256) void xw_kernel(
    const float* __restrict__ x, const float* __restrict__ w,
    float* __restrict__ xw, int r_begin)
{
    __shared__ float w_lds[1024];
    __shared__ float x_lds[32][32];
    const int r = r_begin + blockIdx.y;
    const int base = blockIdx.x * 32;

    for (int i = threadIdx.x; i < 1024; i += 256)
        w_lds[i] = w[r * 1024 + i];
    for (int i = threadIdx.x; i < 1024; i += 256) {
        const int n = i >> 5, c = i & 31;
        const int nn = base + n;
        x_lds[n][c] = (nn < NN) ? x[(size_t)nn * 32 + c] : 0.f;
    }
    __syncthreads();

    const int j0 = threadIdx.x >> 5;   // 0..7
    const int o  = threadIdx.x & 31;
#pragma unroll
    for (int j = j0; j < 32; j += 8) {
        const int nn = base + j;
        if (nn >= NN) continue;
        float acc = 0.f;
#pragma unroll
        for (int i = 0; i < 32; ++i)
            acc += x_lds[j][i] * w_lds[i * 32 + o];
        xw[((size_t)blockIdx.y * NN + nn) * 32 + o] = acc;
    }
}

// ---------------------------------------------------------------------------
// K2: per-edge gather + atomic scatter-add.
// 1 thread per edge: coalesced src/dst/type loads, 8x float4 row gather,
// 32 hardware f32 atomics into acc[dst], optional degree atomic.
// ---------------------------------------------------------------------------
__global__ __launch_bounds__(256) void scatter_kernel(
    const int* __restrict__ src, const int* __restrict__ dst,
    const int* __restrict__ et,  const float* __restrict__ xw,
    float* __restrict__ acc, float* __restrict__ deg,
    int e_begin, int e_count, int r_begin, int with_deg)
{
    const int idx = blockIdx.x * 256 + threadIdx.x;
    if (idx >= e_count) return;
    const int e = e_begin + idx;
    const int s = src[e];
    const int d = dst[e];
    const int t = et[e] - r_begin;    // slot in xw buffer

    const float4* row = reinterpret_cast<const float4*>(xw + ((size_t)t * NN + s) * 32);
    float4 v[8];
#pragma unroll
    for (int k = 0; k < 8; ++k) v[k] = row[k];

    float* ap = acc + (size_t)d * 32;
#pragma unroll
    for (int k = 0; k < 8; ++k) {
        unsafeAtomicAdd(ap + 4 * k + 0, v[k].x);
        unsafeAtomicAdd(ap + 4 * k + 1, v[k].y);
        unsafeAtomicAdd(ap + 4 * k + 2, v[k].z);
        unsafeAtomicAdd(ap + 4 * k + 3, v[k].w);
    }
    if (with_deg) unsafeAtomicAdd(deg + d, 1.0f);
}

// ---------------------------------------------------------------------------
// K3: h = relu(acc / max(deg,1)); write h to ws (optional) and out slice;
// optionally copy x into out cols 0..31.
// grid covers N*32 threads.
// ---------------------------------------------------------------------------
__global__ __launch_bounds__(256) void finalize_kernel(
    const float* __restrict__ x, const float* __restrict__ acc,
    const float* __restrict__ deg, float* __restrict__ h_ws,
    float* __restrict__ out, int col_off, int copy_x)
{
    const int i = blockIdx.x * 256 + threadIdx.x;
    if (i >= NN * 32) return;
    const int n = i >> 5, c = i & 31;
    const float dg = fmaxf(deg[n], 1.0f);
    float v = acc[i] / dg;
    v = fmaxf(v, 0.f);
    if (h_ws) h_ws[i] = v;
    out[(size_t)n * 96 + col_off + c] = v;
    if (copy_x) out[(size_t)n * 96 + c] = x[i];
}

// ---------------------------------------------------------------------------
extern "C" void kernel_launch(void* const* d_in, const int* in_sizes, int n_in,
                              void* d_out, int out_size, void* d_ws, size_t ws_size,
                              hipStream_t stream)
{
    const float* x      = (const float*)d_in[0];
    const int*   ei     = (const int*)d_in[1];
    const int*   et     = (const int*)d_in[2];
    const float* basis0 = (const float*)d_in[4];
    const float* att0   = (const float*)d_in[5];
    const float* basis1 = (const float*)d_in[6];
    const float* att1   = (const float*)d_in[7];
    const int* src = ei;
    const int* dst = ei + EE;
    float* out = (float*)d_out;
    float* ws  = (float*)d_ws;

    // ws layout (floats)
    float* w0  = ws;                          // 8192
    float* w1  = w0 + 8192;                   // 8192
    float* deg = w1 + 8192;                   // NN
    float* acc = deg + NN;                    // NN*32
    float* h1  = acc + (size_t)NN * 32;       // NN*32
    float* xw  = h1  + (size_t)NN * 32;       // R*NN*32 (big) or NN*32 (small)

    const size_t need_big =
        (size_t)(2 * 8192 + NN + 2 * (size_t)NN * 32 + (size_t)RR * NN * 32) * 4;
    const bool big = ws_size >= need_big;

    // zero deg + acc (contiguous)
    hipMemsetAsync(deg, 0, (size_t)(NN + (size_t)NN * 32) * 4, stream);

    compute_w_kernel<<<16, 1024, 0, stream>>>(basis0, att0, basis1, att1, w0, w1);

    const int xw_blocks  = (NN + 31) / 32;       // 3125
    const int fin_blocks = (NN * 32 + 255) / 256; // 12500

    // ---- layer 0 ----
    if (big) {
        xw_kernel<<<dim3(xw_blocks, RR), 256, 0, stream>>>(x, w0, xw, 0);
        scatter_kernel<<<(EE + 255) / 256, 256, 0, stream>>>(
            src, dst, et, xw, acc, deg, 0, EE, 0, 1);
    } else {
        for (int r = 0; r < RR; ++r) {
            xw_kernel<<<dim3(xw_blocks, 1), 256, 0, stream>>>(x, w0, xw, r);
            scatter_kernel<<<(EPER + 255) / 256, 256, 0, stream>>>(
                src, dst, et, xw, acc, deg, r * EPER, EPER, r, 1);
        }
    }
    finalize_kernel<<<fin_blocks, 256, 0, stream>>>(x, acc, deg, h1, out, 32, 1);

    // ---- layer 1 ----
    hipMemsetAsync(acc, 0, (size_t)NN * 32 * 4, stream);
    if (big) {
        xw_kernel<<<dim3(xw_blocks, RR), 256, 0, stream>>>(h1, w1, xw, 0);
        scatter_kernel<<<(EE + 255) / 256, 256, 0, stream>>>(
            src, dst, et, xw, acc, deg, 0, EE, 0, 0);
    } else {
        for (int r = 0; r < RR; ++r) {
            xw_kernel<<<dim3(xw_blocks, 1), 256, 0, stream>>>(h1, w1, xw, r);
            scatter_kernel<<<(EPER + 255) / 256, 256, 0, stream>>>(
                src, dst, et, xw, acc, deg, r * EPER, EPER, r, 0);
        }
    }
    finalize_kernel<<<fin_blocks, 256, 0, stream>>>(x, acc, deg, nullptr, out, 64, 0);
}

// Round 2
// 641.241 us; speedup vs baseline: 13.5080x; 13.5080x over previous
//
#include <hip/hip_runtime.h>

// Problem constants (fixed by setup_inputs)
static constexpr int NN   = 100000;    // nodes
static constexpr int EE   = 2560000;   // edges
static constexpr int RR   = 8;         // relations
static constexpr int BB   = 8;         // bases
static constexpr int EPER = EE / RR;   // 320000 edges per relation

// ---------------------------------------------------------------------------
// K0: w[r][i][o] = sum_b att[r][b] * basis[b][i][o]   for both layers
// grid = 16 blocks (0..7 -> layer0 rel r, 8..15 -> layer1), block = 1024
// ---------------------------------------------------------------------------
__global__ __launch_bounds__(1024) void compute_w_kernel(
    const float* __restrict__ basis0, const float* __restrict__ att0,
    const float* __restrict__ basis1, const float* __restrict__ att1,
    float* __restrict__ w0, float* __restrict__ w1)
{
    const int r = blockIdx.x & 7;
    const bool l0 = blockIdx.x < 8;
    const float* basis = l0 ? basis0 : basis1;
    const float* att   = l0 ? att0   : att1;
    float*       w     = l0 ? w0     : w1;
    const int io = threadIdx.x;           // i*32 + o, 0..1023
    float acc = 0.f;
#pragma unroll
    for (int b = 0; b < BB; ++b)
        acc += att[r * BB + b] * basis[b * 1024 + io];
    w[r * 1024 + io] = acc;
}

// ---------------------------------------------------------------------------
// K1: xw[r][n][o] = sum_i x[n][i] * w[r][i][o]  for ALL 8 relations.
// grid = ceil(N/32), block = 256. x tile read once, reused for all r.
// LDS: 32KB w + 4KB x = 36KB -> 4 blocks/CU.
// ---------------------------------------------------------------------------
__global__ __launch_bounds__(256) void xw_all_kernel(
    const float* __restrict__ x, const float* __restrict__ w,
    float* __restrict__ xw)
{
    __shared__ float w_lds[RR * 1024];
    __shared__ float x_lds[32][32];
    const int base = blockIdx.x * 32;

    for (int i = threadIdx.x; i < RR * 1024; i += 256)
        w_lds[i] = w[i];
    for (int i = threadIdx.x; i < 1024; i += 256) {
        const int n = i >> 5, c = i & 31;
        const int nn = base + n;
        x_lds[n][c] = (nn < NN) ? x[(size_t)nn * 32 + c] : 0.f;
    }
    __syncthreads();

    const int j0 = threadIdx.x >> 5;   // 0..7
    const int o  = threadIdx.x & 31;
#pragma unroll
    for (int r = 0; r < RR; ++r) {
#pragma unroll
        for (int j = j0; j < 32; j += 8) {
            const int nn = base + j;
            if (nn >= NN) continue;
            float acc = 0.f;
#pragma unroll
            for (int i = 0; i < 32; ++i)
                acc += x_lds[j][i] * w_lds[r * 1024 + i * 32 + o];
            xw[((size_t)r * NN + nn) * 32 + o] = acc;
        }
    }
}

// ---------------------------------------------------------------------------
// CSR build: histogram by dst -> exclusive scan -> bucket fill.
// ---------------------------------------------------------------------------
__global__ __launch_bounds__(256) void hist_kernel(
    const int* __restrict__ dst, int* __restrict__ cnt)
{
    const int e = blockIdx.x * 256 + threadIdx.x;
    if (e < EE) atomicAdd(&cnt[dst[e]], 1);
}

// scan1: per-block inclusive scan -> exclusive per element into row_start,
// block total into partials[blockIdx].
__global__ __launch_bounds__(256) void scan1_kernel(
    const int* __restrict__ cnt, int* __restrict__ row_start,
    int* __restrict__ partials)
{
    __shared__ int s[256];
    const int i = blockIdx.x * 256 + threadIdx.x;
    const int v = (i < NN) ? cnt[i] : 0;
    s[threadIdx.x] = v;
    __syncthreads();
    for (int off = 1; off < 256; off <<= 1) {
        const int t = (threadIdx.x >= off) ? s[threadIdx.x - off] : 0;
        __syncthreads();
        s[threadIdx.x] += t;
        __syncthreads();
    }
    if (i < NN) row_start[i] = s[threadIdx.x] - v;   // exclusive within block
    if (threadIdx.x == 255) partials[blockIdx.x] = s[255];
}

// scan2: exclusive scan of block totals (<=512 of them), single block.
__global__ __launch_bounds__(512) void scan2_kernel(int* __restrict__ partials)
{
    __shared__ int s[512];
    const int v = partials[threadIdx.x];
    s[threadIdx.x] = v;
    __syncthreads();
    for (int off = 1; off < 512; off <<= 1) {
        const int t = (threadIdx.x >= off) ? s[threadIdx.x - off] : 0;
        __syncthreads();
        s[threadIdx.x] += t;
        __syncthreads();
    }
    partials[threadIdx.x] = s[threadIdx.x] - v;      // exclusive
}

// scan3: add block offsets; set row_start[NN] = EE.
__global__ __launch_bounds__(256) void scan3_kernel(
    int* __restrict__ row_start, const int* __restrict__ partials)
{
    const int i = blockIdx.x * 256 + threadIdx.x;
    if (i < NN) row_start[i] += partials[blockIdx.x];
    if (i == NN) row_start[NN] = EE;
}

// fill: payload[pos] = et*NN + src, bucketed by dst. cnt must be re-zeroed.
__global__ __launch_bounds__(256) void fill_kernel(
    const int* __restrict__ src, const int* __restrict__ dst,
    const int* __restrict__ et, const int* __restrict__ row_start,
    int* __restrict__ cnt, int* __restrict__ payload)
{
    const int e = blockIdx.x * 256 + threadIdx.x;
    if (e >= EE) return;
    const int d = dst[e];
    const int pos = row_start[d] + atomicAdd(&cnt[d], 1);
    payload[pos] = et[e] * NN + src[e];
}

// ---------------------------------------------------------------------------
// K2: gather-side reduction. One 32-lane group per node, lane = dim.
// Payload chunk-loaded coalesced, broadcast via shfl; xw rows are 128B
// coalesced reads (L3-resident). Fused relu(acc/deg) + output writes.
// ---------------------------------------------------------------------------
__global__ __launch_bounds__(256) void gather_kernel(
    const float* __restrict__ xw, const int* __restrict__ row_start,
    const int* __restrict__ payload, const float* __restrict__ x,
    float* __restrict__ h_ws, float* __restrict__ out,
    int col_off, int copy_x)
{
    const int g    = (blockIdx.x * 256 + threadIdx.x) >> 5;  // node id
    const int lane = threadIdx.x & 31;
    if (g >= NN) return;
    const int e0 = row_start[g];
    const int e1 = row_start[g + 1];

    float acc = 0.f;
    for (int eb = e0; eb < e1; eb += 32) {
        const int nloc = min(32, e1 - eb);
        const int p = (lane < nloc) ? payload[eb + lane] : 0;
        int k = 0;
        for (; k + 1 < nloc; k += 2) {
            const int s0 = __shfl(p, k, 32);
            const int s1 = __shfl(p, k + 1, 32);
            const float a = xw[(size_t)s0 * 32 + lane];
            const float b = xw[(size_t)s1 * 32 + lane];
            acc += a;
            acc += b;
        }
        if (k < nloc)
            acc += xw[(size_t)__shfl(p, k, 32) * 32 + lane];
    }

    const float dg = fmaxf((float)(e1 - e0), 1.0f);
    const float v = fmaxf(acc / dg, 0.f);
    if (h_ws) h_ws[(size_t)g * 32 + lane] = v;
    out[(size_t)g * 96 + col_off + lane] = v;
    if (copy_x) out[(size_t)g * 96 + lane] = x[(size_t)g * 32 + lane];
}

// ---------------------------------------------------------------------------
// Fallback path kernels (small workspace): atomic scatter + finalize.
// ---------------------------------------------------------------------------
__global__ __launch_bounds__(256) void scatter_kernel(
    const int* __restrict__ src, const int* __restrict__ dst,
    const int* __restrict__ et,  const float* __restrict__ xw,
    float* __restrict__ acc, float* __restrict__ deg,
    int e_begin, int e_count, int r_begin, int with_deg)
{
    const int idx = blockIdx.x * 256 + threadIdx.x;
    if (idx >= e_count) return;
    const int e = e_begin + idx;
    const int s = src[e];
    const int d = dst[e];
    const int t = et[e] - r_begin;

    const float4* row = reinterpret_cast<const float4*>(xw + ((size_t)t * NN + s) * 32);
    float4 v[8];
#pragma unroll
    for (int k = 0; k < 8; ++k) v[k] = row[k];

    float* ap = acc + (size_t)d * 32;
#pragma unroll
    for (int k = 0; k < 8; ++k) {
        unsafeAtomicAdd(ap + 4 * k + 0, v[k].x);
        unsafeAtomicAdd(ap + 4 * k + 1, v[k].y);
        unsafeAtomicAdd(ap + 4 * k + 2, v[k].z);
        unsafeAtomicAdd(ap + 4 * k + 3, v[k].w);
    }
    if (with_deg) unsafeAtomicAdd(deg + d, 1.0f);
}

__global__ __launch_bounds__(256) void finalize_kernel(
    const float* __restrict__ x, const float* __restrict__ acc,
    const float* __restrict__ deg, float* __restrict__ h_ws,
    float* __restrict__ out, int col_off, int copy_x)
{
    const int i = blockIdx.x * 256 + threadIdx.x;
    if (i >= NN * 32) return;
    const int n = i >> 5, c = i & 31;
    const float dg = fmaxf(deg[n], 1.0f);
    float v = fmaxf(acc[i] / dg, 0.f);
    if (h_ws) h_ws[i] = v;
    out[(size_t)n * 96 + col_off + c] = v;
    if (copy_x) out[(size_t)n * 96 + c] = x[i];
}

// ---------------------------------------------------------------------------
__global__ __launch_bounds__(256) void xw_one_kernel(
    const float* __restrict__ x, const float* __restrict__ w,
    float* __restrict__ xw, int r)
{
    __shared__ float w_lds[1024];
    __shared__ float x_lds[32][32];
    const int base = blockIdx.x * 32;
    for (int i = threadIdx.x; i < 1024; i += 256)
        w_lds[i] = w[r * 1024 + i];
    for (int i = threadIdx.x; i < 1024; i += 256) {
        const int n = i >> 5, c = i & 31;
        const int nn = base + n;
        x_lds[n][c] = (nn < NN) ? x[(size_t)nn * 32 + c] : 0.f;
    }
    __syncthreads();
    const int j0 = threadIdx.x >> 5;
    const int o  = threadIdx.x & 31;
#pragma unroll
    for (int j = j0; j < 32; j += 8) {
        const int nn = base + j;
        if (nn >= NN) continue;
        float acc = 0.f;
#pragma unroll
        for (int i = 0; i < 32; ++i)
            acc += x_lds[j][i] * w_lds[i * 32 + o];
        xw[(size_t)nn * 32 + o] = acc;
    }
}

// ---------------------------------------------------------------------------
extern "C" void kernel_launch(void* const* d_in, const int* in_sizes, int n_in,
                              void* d_out, int out_size, void* d_ws, size_t ws_size,
                              hipStream_t stream)
{
    const float* x      = (const float*)d_in[0];
    const int*   ei     = (const int*)d_in[1];
    const int*   et     = (const int*)d_in[2];
    const float* basis0 = (const float*)d_in[4];
    const float* att0   = (const float*)d_in[5];
    const float* basis1 = (const float*)d_in[6];
    const float* att1   = (const float*)d_in[7];
    const int* src = ei;
    const int* dst = ei + EE;
    float* out = (float*)d_out;
    float* ws  = (float*)d_ws;

    const int xw_blocks   = (NN + 31) / 32;        // 3125
    const int edge_blocks = (EE + 255) / 256;      // 10000
    const int scan_blocks = (NN + 255) / 256;      // 391
    const int node_blocks = (NN * 32 + 255) / 256; // 12500

    // ---- big path layout (floats/ints, 4B each) ----
    float* w0        = ws;                                   // 8192
    float* w1        = w0 + 8192;                            // 8192
    int*   row_start = (int*)(w1 + 8192);                    // NN+1
    int*   cnt       = row_start + NN + 1;                   // NN
    int*   partials  = cnt + NN;                             // 512
    int*   payload   = partials + 512;                       // EE
    float* h1        = (float*)(payload + EE);               // NN*32
    float* xw        = h1 + (size_t)NN * 32;                 // RR*NN*32

    const size_t need_big =
        ((size_t)2 * 8192 + (NN + 1) + NN + 512 + EE +
         (size_t)NN * 32 + (size_t)RR * NN * 32) * 4;

    if (ws_size >= need_big) {
        compute_w_kernel<<<16, 1024, 0, stream>>>(basis0, att0, basis1, att1, w0, w1);

        // ---- CSR build (once, reused by both layers) ----
        hipMemsetAsync(cnt, 0, (size_t)NN * 4, stream);
        hist_kernel<<<edge_blocks, 256, 0, stream>>>(dst, cnt);
        scan1_kernel<<<scan_blocks, 256, 0, stream>>>(cnt, row_start, partials);
        scan2_kernel<<<1, 512, 0, stream>>>(partials);
        scan3_kernel<<<scan_blocks, 256, 0, stream>>>(row_start, partials);
        hipMemsetAsync(cnt, 0, (size_t)NN * 4, stream);
        fill_kernel<<<edge_blocks, 256, 0, stream>>>(src, dst, et, row_start, cnt, payload);

        // ---- layer 0 ----
        xw_all_kernel<<<xw_blocks, 256, 0, stream>>>(x, w0, xw);
        gather_kernel<<<node_blocks, 256, 0, stream>>>(
            xw, row_start, payload, x, h1, out, 32, 1);

        // ---- layer 1 ----
        xw_all_kernel<<<xw_blocks, 256, 0, stream>>>(h1, w1, xw);
        gather_kernel<<<node_blocks, 256, 0, stream>>>(
            xw, row_start, payload, x, nullptr, out, 64, 0);
        return;
    }

    // ---- fallback: small workspace, per-relation atomic scatter ----
    float* deg  = (float*)(w1 + 8192);            // NN
    float* acc  = deg + NN;                       // NN*32
    float* h1s  = acc + (size_t)NN * 32;          // NN*32
    float* xws  = h1s + (size_t)NN * 32;          // NN*32

    hipMemsetAsync(deg, 0, (size_t)(NN + (size_t)NN * 32) * 4, stream);
    compute_w_kernel<<<16, 1024, 0, stream>>>(basis0, att0, basis1, att1, w0, w1);

    for (int r = 0; r < RR; ++r) {
        xw_one_kernel<<<xw_blocks, 256, 0, stream>>>(x, w0, xws, r);
        scatter_kernel<<<(EPER + 255) / 256, 256, 0, stream>>>(
            src, dst, et, xws, acc, deg, r * EPER, EPER, r, 1);
    }
    finalize_kernel<<<node_blocks, 256, 0, stream>>>(x, acc, deg, h1s, out, 32, 1);

    hipMemsetAsync(acc, 0, (size_t)NN * 32 * 4, stream);
    for (int r = 0; r < RR; ++r) {
        xw_one_kernel<<<xw_blocks, 256, 0, stream>>>(h1s, w1, xws, r);
        scatter_kernel<<<(EPER + 255) / 256, 256, 0, stream>>>(
            src, dst, et, xws, acc, deg, r * EPER, EPER, r, 0);
    }
    finalize_kernel<<<node_blocks, 256, 0, stream>>>(x, acc, deg, nullptr, out, 64, 0);
}

// Round 3
// 591.582 us; speedup vs baseline: 14.6419x; 1.0839x over previous
//
#include <hip/hip_runtime.h>

// Problem constants (fixed by setup_inputs)
static constexpr int NN   = 100000;    // nodes
static constexpr int EE   = 2560000;   // edges
static constexpr int RR   = 8;         // relations
static constexpr int BB   = 8;         // bases
static constexpr int EPER = EE / RR;   // 320000 edges per relation

// dst-partitioned CSR build: P windows of CHUNK nodes each
static constexpr int PPART = 8;
static constexpr int CHUNK = (NN + PPART - 1) / PPART;  // 12500

// ---------------------------------------------------------------------------
// K0: w[r][i][o] = sum_b att[r][b] * basis[b][i][o]   for both layers
// ---------------------------------------------------------------------------
__global__ __launch_bounds__(1024) void compute_w_kernel(
    const float* __restrict__ basis0, const float* __restrict__ att0,
    const float* __restrict__ basis1, const float* __restrict__ att1,
    float* __restrict__ w0, float* __restrict__ w1)
{
    const int r = blockIdx.x & 7;
    const bool l0 = blockIdx.x < 8;
    const float* basis = l0 ? basis0 : basis1;
    const float* att   = l0 ? att0   : att1;
    float*       w     = l0 ? w0     : w1;
    const int io = threadIdx.x;           // i*32 + o, 0..1023
    float acc = 0.f;
#pragma unroll
    for (int b = 0; b < BB; ++b)
        acc += att[r * BB + b] * basis[b * 1024 + io];
    w[r * 1024 + io] = acc;
}

// ---------------------------------------------------------------------------
// K1: xw[r][n][o] = sum_i x[n][i] * w[r][i][o]  for ALL 8 relations.
// ---------------------------------------------------------------------------
__global__ __launch_bounds__(256) void xw_all_kernel(
    const float* __restrict__ x, const float* __restrict__ w,
    float* __restrict__ xw)
{
    __shared__ float w_lds[RR * 1024];
    __shared__ float x_lds[32][32];
    const int base = blockIdx.x * 32;

    for (int i = threadIdx.x; i < RR * 1024; i += 256)
        w_lds[i] = w[i];
    for (int i = threadIdx.x; i < 1024; i += 256) {
        const int n = i >> 5, c = i & 31;
        const int nn = base + n;
        x_lds[n][c] = (nn < NN) ? x[(size_t)nn * 32 + c] : 0.f;
    }
    __syncthreads();

    const int j0 = threadIdx.x >> 5;   // 0..7
    const int o  = threadIdx.x & 31;
#pragma unroll
    for (int r = 0; r < RR; ++r) {
#pragma unroll
        for (int j = j0; j < 32; j += 8) {
            const int nn = base + j;
            if (nn >= NN) continue;
            float acc = 0.f;
#pragma unroll
            for (int i = 0; i < 32; ++i)
                acc += x_lds[j][i] * w_lds[r * 1024 + i * 32 + o];
            xw[((size_t)r * NN + nn) * 32 + o] = acc;
        }
    }
}

// ---------------------------------------------------------------------------
// CSR build, dst-partitioned. pass = blockIdx.x & 7 so that (with round-robin
// block->XCD dispatch) each dst-window's writes/atomics stay in one XCD's L2.
// ---------------------------------------------------------------------------
__global__ __launch_bounds__(256) void hist_part_kernel(
    const int* __restrict__ dst, int* __restrict__ cnt)
{
    const int pass = blockIdx.x & (PPART - 1);
    const int e = (blockIdx.x >> 3) * 256 + threadIdx.x;
    if (e >= EE) return;
    const int d = dst[e];
    const int lo = pass * CHUNK;
    if (d >= lo && d < lo + CHUNK) atomicAdd(&cnt[d], 1);
}

// scan1: per-block inclusive scan -> exclusive per element into row_start,
// block total into partials[blockIdx].
__global__ __launch_bounds__(256) void scan1_kernel(
    const int* __restrict__ cnt, int* __restrict__ row_start,
    int* __restrict__ partials)
{
    __shared__ int s[256];
    const int i = blockIdx.x * 256 + threadIdx.x;
    const int v = (i < NN) ? cnt[i] : 0;
    s[threadIdx.x] = v;
    __syncthreads();
    for (int off = 1; off < 256; off <<= 1) {
        const int t = (threadIdx.x >= off) ? s[threadIdx.x - off] : 0;
        __syncthreads();
        s[threadIdx.x] += t;
        __syncthreads();
    }
    if (i < NN) row_start[i] = s[threadIdx.x] - v;   // exclusive within block
    if (threadIdx.x == 255) partials[blockIdx.x] = s[255];
}

// scan2: exclusive scan of block totals (<=512 of them), single block.
__global__ __launch_bounds__(512) void scan2_kernel(int* __restrict__ partials)
{
    __shared__ int s[512];
    const int v = partials[threadIdx.x];
    s[threadIdx.x] = v;
    __syncthreads();
    for (int off = 1; off < 512; off <<= 1) {
        const int t = (threadIdx.x >= off) ? s[threadIdx.x - off] : 0;
        __syncthreads();
        s[threadIdx.x] += t;
        __syncthreads();
    }
    partials[threadIdx.x] = s[threadIdx.x] - v;      // exclusive
}

// scan3: add block offsets; set row_start[NN] = EE.
__global__ __launch_bounds__(256) void scan3_kernel(
    int* __restrict__ row_start, const int* __restrict__ partials)
{
    const int i = blockIdx.x * 256 + threadIdx.x;
    if (i < NN) row_start[i] += partials[blockIdx.x];
    if (i == NN) row_start[NN] = EE;
}

// fill (partitioned): payload[pos] = et*NN + src, bucketed by dst.
// et computed as e / EPER (edges sorted by type, equal blocks) -> no et load.
__global__ __launch_bounds__(256) void fill_part_kernel(
    const int* __restrict__ src, const int* __restrict__ dst,
    const int* __restrict__ row_start, int* __restrict__ cnt,
    int* __restrict__ payload)
{
    const int pass = blockIdx.x & (PPART - 1);
    const int e = (blockIdx.x >> 3) * 256 + threadIdx.x;
    if (e >= EE) return;
    const int d = dst[e];
    const int lo = pass * CHUNK;
    if (d < lo || d >= lo + CHUNK) return;
    const int t = e / EPER;
    const int pos = row_start[d] + atomicAdd(&cnt[d], 1);
    payload[pos] = t * NN + src[e];
}

// ---------------------------------------------------------------------------
// K2: gather-side reduction. One 32-lane group per node, lane = dim.
// ---------------------------------------------------------------------------
__global__ __launch_bounds__(256) void gather_kernel(
    const float* __restrict__ xw, const int* __restrict__ row_start,
    const int* __restrict__ payload, const float* __restrict__ x,
    float* __restrict__ h_ws, float* __restrict__ out,
    int col_off, int copy_x)
{
    const int g    = (blockIdx.x * 256 + threadIdx.x) >> 5;  // node id
    const int lane = threadIdx.x & 31;
    if (g >= NN) return;
    const int e0 = row_start[g];
    const int e1 = row_start[g + 1];

    float acc = 0.f;
    for (int eb = e0; eb < e1; eb += 32) {
        const int nloc = min(32, e1 - eb);
        const int p = (lane < nloc) ? payload[eb + lane] : 0;
        int k = 0;
        for (; k + 3 < nloc; k += 4) {
            const int s0 = __shfl(p, k,     32);
            const int s1 = __shfl(p, k + 1, 32);
            const int s2 = __shfl(p, k + 2, 32);
            const int s3 = __shfl(p, k + 3, 32);
            const float a = xw[(size_t)s0 * 32 + lane];
            const float b = xw[(size_t)s1 * 32 + lane];
            const float c = xw[(size_t)s2 * 32 + lane];
            const float d = xw[(size_t)s3 * 32 + lane];
            acc += a; acc += b; acc += c; acc += d;
        }
        for (; k < nloc; ++k)
            acc += xw[(size_t)__shfl(p, k, 32) * 32 + lane];
    }

    const float dg = fmaxf((float)(e1 - e0), 1.0f);
    const float v = fmaxf(acc / dg, 0.f);
    if (h_ws) h_ws[(size_t)g * 32 + lane] = v;
    out[(size_t)g * 96 + col_off + lane] = v;
    if (copy_x) out[(size_t)g * 96 + lane] = x[(size_t)g * 32 + lane];
}

// ---------------------------------------------------------------------------
// Fallback path kernels (small workspace): atomic scatter + finalize.
// ---------------------------------------------------------------------------
__global__ __launch_bounds__(256) void scatter_kernel(
    const int* __restrict__ src, const int* __restrict__ dst,
    const int* __restrict__ et,  const float* __restrict__ xw,
    float* __restrict__ acc, float* __restrict__ deg,
    int e_begin, int e_count, int r_begin, int with_deg)
{
    const int idx = blockIdx.x * 256 + threadIdx.x;
    if (idx >= e_count) return;
    const int e = e_begin + idx;
    const int s = src[e];
    const int d = dst[e];
    const int t = et[e] - r_begin;

    const float4* row = reinterpret_cast<const float4*>(xw + ((size_t)t * NN + s) * 32);
    float4 v[8];
#pragma unroll
    for (int k = 0; k < 8; ++k) v[k] = row[k];

    float* ap = acc + (size_t)d * 32;
#pragma unroll
    for (int k = 0; k < 8; ++k) {
        unsafeAtomicAdd(ap + 4 * k + 0, v[k].x);
        unsafeAtomicAdd(ap + 4 * k + 1, v[k].y);
        unsafeAtomicAdd(ap + 4 * k + 2, v[k].z);
        unsafeAtomicAdd(ap + 4 * k + 3, v[k].w);
    }
    if (with_deg) unsafeAtomicAdd(deg + d, 1.0f);
}

__global__ __launch_bounds__(256) void finalize_kernel(
    const float* __restrict__ x, const float* __restrict__ acc,
    const float* __restrict__ deg, float* __restrict__ h_ws,
    float* __restrict__ out, int col_off, int copy_x)
{
    const int i = blockIdx.x * 256 + threadIdx.x;
    if (i >= NN * 32) return;
    const int n = i >> 5, c = i & 31;
    const float dg = fmaxf(deg[n], 1.0f);
    float v = fmaxf(acc[i] / dg, 0.f);
    if (h_ws) h_ws[i] = v;
    out[(size_t)n * 96 + col_off + c] = v;
    if (copy_x) out[(size_t)n * 96 + c] = x[i];
}

__global__ __launch_bounds__(256) void xw_one_kernel(
    const float* __restrict__ x, const float* __restrict__ w,
    float* __restrict__ xw, int r)
{
    __shared__ float w_lds[1024];
    __shared__ float x_lds[32][32];
    const int base = blockIdx.x * 32;
    for (int i = threadIdx.x; i < 1024; i += 256)
        w_lds[i] = w[r * 1024 + i];
    for (int i = threadIdx.x; i < 1024; i += 256) {
        const int n = i >> 5, c = i & 31;
        const int nn = base + n;
        x_lds[n][c] = (nn < NN) ? x[(size_t)nn * 32 + c] : 0.f;
    }
    __syncthreads();
    const int j0 = threadIdx.x >> 5;
    const int o  = threadIdx.x & 31;
#pragma unroll
    for (int j = j0; j < 32; j += 8) {
        const int nn = base + j;
        if (nn >= NN) continue;
        float acc = 0.f;
#pragma unroll
        for (int i = 0; i < 32; ++i)
            acc += x_lds[j][i] * w_lds[i * 32 + o];
        xw[(size_t)nn * 32 + o] = acc;
    }
}

// ---------------------------------------------------------------------------
extern "C" void kernel_launch(void* const* d_in, const int* in_sizes, int n_in,
                              void* d_out, int out_size, void* d_ws, size_t ws_size,
                              hipStream_t stream)
{
    const float* x      = (const float*)d_in[0];
    const int*   ei     = (const int*)d_in[1];
    const int*   et     = (const int*)d_in[2];
    const float* basis0 = (const float*)d_in[4];
    const float* att0   = (const float*)d_in[5];
    const float* basis1 = (const float*)d_in[6];
    const float* att1   = (const float*)d_in[7];
    const int* src = ei;
    const int* dst = ei + EE;
    float* out = (float*)d_out;
    float* ws  = (float*)d_ws;

    const int xw_blocks   = (NN + 31) / 32;        // 3125
    const int edge_blocks = (EE + 255) / 256;      // 10000
    const int scan_blocks = (NN + 255) / 256;      // 391
    const int node_blocks = (NN * 32 + 255) / 256; // 12500

    // ---- big path layout (floats/ints, 4B each) ----
    float* w0        = ws;                                   // 8192
    float* w1        = w0 + 8192;                            // 8192
    int*   row_start = (int*)(w1 + 8192);                    // NN+1
    int*   cnt       = row_start + NN + 1;                   // NN
    int*   partials  = cnt + NN;                             // 512
    int*   payload   = partials + 512;                       // EE
    float* h1        = (float*)(payload + EE);               // NN*32
    float* xw        = h1 + (size_t)NN * 32;                 // RR*NN*32

    const size_t need_big =
        ((size_t)2 * 8192 + (NN + 1) + NN + 512 + EE +
         (size_t)NN * 32 + (size_t)RR * NN * 32) * 4;

    if (ws_size >= need_big) {
        compute_w_kernel<<<16, 1024, 0, stream>>>(basis0, att0, basis1, att1, w0, w1);

        // ---- CSR build (once, reused by both layers) ----
        hipMemsetAsync(cnt, 0, (size_t)NN * 4, stream);
        hist_part_kernel<<<PPART * edge_blocks, 256, 0, stream>>>(dst, cnt);
        scan1_kernel<<<scan_blocks, 256, 0, stream>>>(cnt, row_start, partials);
        scan2_kernel<<<1, 512, 0, stream>>>(partials);
        scan3_kernel<<<scan_blocks, 256, 0, stream>>>(row_start, partials);
        hipMemsetAsync(cnt, 0, (size_t)NN * 4, stream);
        fill_part_kernel<<<PPART * edge_blocks, 256, 0, stream>>>(
            src, dst, row_start, cnt, payload);

        // ---- layer 0 ----
        xw_all_kernel<<<xw_blocks, 256, 0, stream>>>(x, w0, xw);
        gather_kernel<<<node_blocks, 256, 0, stream>>>(
            xw, row_start, payload, x, h1, out, 32, 1);

        // ---- layer 1 ----
        xw_all_kernel<<<xw_blocks, 256, 0, stream>>>(h1, w1, xw);
        gather_kernel<<<node_blocks, 256, 0, stream>>>(
            xw, row_start, payload, x, nullptr, out, 64, 0);
        return;
    }

    // ---- fallback: small workspace, per-relation atomic scatter ----
    float* deg  = (float*)(w1 + 8192);            // NN
    float* acc  = deg + NN;                       // NN*32
    float* h1s  = acc + (size_t)NN * 32;          // NN*32
    float* xws  = h1s + (size_t)NN * 32;          // NN*32

    hipMemsetAsync(deg, 0, (size_t)(NN + (size_t)NN * 32) * 4, stream);
    compute_w_kernel<<<16, 1024, 0, stream>>>(basis0, att0, basis1, att1, w0, w1);

    for (int r = 0; r < RR; ++r) {
        xw_one_kernel<<<xw_blocks, 256, 0, stream>>>(x, w0, xws, r);
        scatter_kernel<<<(EPER + 255) / 256, 256, 0, stream>>>(
            src, dst, et, xws, acc, deg, r * EPER, EPER, r, 1);
    }
    finalize_kernel<<<node_blocks, 256, 0, stream>>>(x, acc, deg, h1s, out, 32, 1);

    hipMemsetAsync(acc, 0, (size_t)NN * 32 * 4, stream);
    for (int r = 0; r < RR; ++r) {
        xw_one_kernel<<<xw_blocks, 256, 0, stream>>>(h1s, w1, xws, r);
        scatter_kernel<<<(EPER + 255) / 256, 256, 0, stream>>>(
            src, dst, et, xws, acc, deg, r * EPER, EPER, r, 0);
    }
    finalize_kernel<<<node_blocks, 256, 0, stream>>>(x, acc, deg, nullptr, out, 64, 0);
}

// Round 4
// 412.282 us; speedup vs baseline: 21.0096x; 1.4349x over previous
//
#include <hip/hip_runtime.h>

// Problem constants (fixed by setup_inputs)
static constexpr int NN   = 100000;    // nodes
static constexpr int EE   = 2560000;   // edges
static constexpr int RR   = 8;         // relations
static constexpr int BB   = 8;         // bases
static constexpr int EPER = EE / RR;   // 320000 edges per relation

// Bucketed CSR build: bucket = dst >> 8 (256 nodes per bucket)
static constexpr int NB      = (NN + 255) / 256;   // 391 buckets
static constexpr int CHUNK_E = 8192;               // edges per block in hist/fill
static constexpr int EB      = (EE + CHUNK_E - 1) / CHUNK_E;  // 313 blocks

// ---------------------------------------------------------------------------
// K0: w[r][i][o] = sum_b att[r][b] * basis[b][i][o]   for both layers
// ---------------------------------------------------------------------------
__global__ __launch_bounds__(1024) void compute_w_kernel(
    const float* __restrict__ basis0, const float* __restrict__ att0,
    const float* __restrict__ basis1, const float* __restrict__ att1,
    float* __restrict__ w0, float* __restrict__ w1)
{
    const int r = blockIdx.x & 7;
    const bool l0 = blockIdx.x < 8;
    const float* basis = l0 ? basis0 : basis1;
    const float* att   = l0 ? att0   : att1;
    float*       w     = l0 ? w0     : w1;
    const int io = threadIdx.x;           // i*32 + o, 0..1023
    float acc = 0.f;
#pragma unroll
    for (int b = 0; b < BB; ++b)
        acc += att[r * BB + b] * basis[b * 1024 + io];
    w[r * 1024 + io] = acc;
}

// ---------------------------------------------------------------------------
// K1: xw[r][n][o] = sum_i x[n][i] * w[r][i][o].  r = blockIdx.y.
// x row in VGPRs; w accessed with wave-uniform indices -> s_load (SGPR),
// so the inner 1024 FMAs are pure VALU with no LDS traffic.
// ---------------------------------------------------------------------------
__global__ __launch_bounds__(256) void xw_reg_kernel(
    const float* __restrict__ x, const float* __restrict__ w,
    float* __restrict__ xw)
{
    const int n = blockIdx.x * 256 + threadIdx.x;
    if (n >= NN) return;
    const int r = blockIdx.y;

    float xr[32];
    const float4* xp = reinterpret_cast<const float4*>(x + (size_t)n * 32);
#pragma unroll
    for (int q = 0; q < 8; ++q) {
        const float4 v = xp[q];
        xr[4 * q + 0] = v.x; xr[4 * q + 1] = v.y;
        xr[4 * q + 2] = v.z; xr[4 * q + 3] = v.w;
    }

    float acc[32];
#pragma unroll
    for (int o = 0; o < 32; ++o) acc[o] = 0.f;

    const float* wr = w + r * 1024;      // wave-uniform base
#pragma unroll
    for (int i = 0; i < 32; ++i) {
        const float xv = xr[i];
#pragma unroll
        for (int o = 0; o < 32; ++o)
            acc[o] += xv * wr[i * 32 + o];   // uniform index -> s_load
    }

    float4* op = reinterpret_cast<float4*>(xw + ((size_t)r * NN + n) * 32);
#pragma unroll
    for (int q = 0; q < 8; ++q)
        op[q] = make_float4(acc[4 * q], acc[4 * q + 1], acc[4 * q + 2], acc[4 * q + 3]);
}

// ---------------------------------------------------------------------------
// CSR build, two-level bucket sort. No per-edge global atomics.
// ---------------------------------------------------------------------------
// PassH: per-block LDS histogram over NB buckets, one global atomic per
// (block, nonzero bucket)  ->  ~122k atomics instead of 2.56M.
__global__ __launch_bounds__(256) void bucket_hist_kernel(
    const int* __restrict__ dst, int* __restrict__ bucket_cnt)
{
    __shared__ int h[NB];
    for (int i = threadIdx.x; i < NB; i += 256) h[i] = 0;
    __syncthreads();
    const int base = blockIdx.x * CHUNK_E;
    for (int k = threadIdx.x; k < CHUNK_E; k += 256) {
        const int e = base + k;
        if (e < EE) atomicAdd(&h[dst[e] >> 8], 1);
    }
    __syncthreads();
    for (int i = threadIdx.x; i < NB; i += 256)
        if (h[i]) atomicAdd(&bucket_cnt[i], h[i]);
}

// Scan bucket totals (NB <= 512), init cursor = edge_base.
__global__ __launch_bounds__(512) void bucket_scan_kernel(
    const int* __restrict__ bucket_cnt, int* __restrict__ edge_base,
    int* __restrict__ cursor)
{
    __shared__ int s[512];
    const int v = (threadIdx.x < NB) ? bucket_cnt[threadIdx.x] : 0;
    s[threadIdx.x] = v;
    __syncthreads();
    for (int off = 1; off < 512; off <<= 1) {
        const int t = (threadIdx.x >= off) ? s[threadIdx.x - off] : 0;
        __syncthreads();
        s[threadIdx.x] += t;
        __syncthreads();
    }
    if (threadIdx.x < NB) {
        const int ex = s[threadIdx.x] - v;
        edge_base[threadIdx.x] = ex;
        cursor[threadIdx.x]    = ex;
    }
    if (threadIdx.x == NB) edge_base[NB] = EE;
}

// PassA: local hist -> one cursor reservation per (block,bucket) -> write
// contiguous runs of int2(dst, t*NN+src) into the bucket regions.
__global__ __launch_bounds__(256) void bucket_fill_kernel(
    const int* __restrict__ src, const int* __restrict__ dst,
    int* __restrict__ cursor, int2* __restrict__ pairs)
{
    __shared__ int h[NB];
    __shared__ int base_s[NB];
    for (int i = threadIdx.x; i < NB; i += 256) h[i] = 0;
    __syncthreads();
    const int base = blockIdx.x * CHUNK_E;
    for (int k = threadIdx.x; k < CHUNK_E; k += 256) {
        const int e = base + k;
        if (e < EE) atomicAdd(&h[dst[e] >> 8], 1);
    }
    __syncthreads();
    for (int i = threadIdx.x; i < NB; i += 256) {
        const int c = h[i];
        base_s[i] = c ? atomicAdd(&cursor[i], c) : 0;
    }
    __syncthreads();
    for (int i = threadIdx.x; i < NB; i += 256) h[i] = 0;
    __syncthreads();
    for (int k = threadIdx.x; k < CHUNK_E; k += 256) {
        const int e = base + k;
        if (e >= EE) continue;
        const int d = dst[e];
        const int b = d >> 8;
        const int pos = base_s[b] + atomicAdd(&h[b], 1);   // LDS atomic only
        const int t = e / EPER;     // edges sorted by type, equal blocks
        pairs[pos] = make_int2(d, t * NN + src[e]);
    }
}

// PassB: one block per bucket (256 nodes). LDS hist + scan -> row_start,
// then LDS-rank scatter of payload within the bucket's small window.
__global__ __launch_bounds__(256) void bucket_sort_kernel(
    const int2* __restrict__ pairs, const int* __restrict__ edge_base,
    int* __restrict__ row_start, int* __restrict__ payload)
{
    __shared__ int cnt_s[256];
    __shared__ int s[256];
    __shared__ int rs_s[256];
    const int b  = blockIdx.x;
    const int e0 = edge_base[b];
    const int e1 = edge_base[b + 1];

    cnt_s[threadIdx.x] = 0;
    __syncthreads();
    for (int k = e0 + threadIdx.x; k < e1; k += 256)
        atomicAdd(&cnt_s[pairs[k].x & 255], 1);
    __syncthreads();

    const int v = cnt_s[threadIdx.x];
    s[threadIdx.x] = v;
    __syncthreads();
    for (int off = 1; off < 256; off <<= 1) {
        const int t = (threadIdx.x >= off) ? s[threadIdx.x - off] : 0;
        __syncthreads();
        s[threadIdx.x] += t;
        __syncthreads();
    }
    rs_s[threadIdx.x] = s[threadIdx.x] - v;     // exclusive, bucket-relative

    const int n = (b << 8) + threadIdx.x;
    if (n <= NN) row_start[n] = e0 + rs_s[threadIdx.x];
    // (last bucket: counts for n>=NN are 0, so row_start[NN] lands on e1=EE)

    __syncthreads();
    cnt_s[threadIdx.x] = 0;                     // reuse as rank
    __syncthreads();
    for (int k = e0 + threadIdx.x; k < e1; k += 256) {
        const int2 pr = pairs[k];
        const int loc = pr.x & 255;
        const int pos = e0 + rs_s[loc] + atomicAdd(&cnt_s[loc], 1);
        payload[pos] = pr.y;
    }
}

// ---------------------------------------------------------------------------
// K2: gather-side reduction. One 32-lane group per node, lane = dim.
// ---------------------------------------------------------------------------
__global__ __launch_bounds__(256) void gather_kernel(
    const float* __restrict__ xw, const int* __restrict__ row_start,
    const int* __restrict__ payload, const float* __restrict__ x,
    float* __restrict__ h_ws, float* __restrict__ out,
    int col_off, int copy_x)
{
    const int g    = (blockIdx.x * 256 + threadIdx.x) >> 5;  // node id
    const int lane = threadIdx.x & 31;
    if (g >= NN) return;
    const int e0 = row_start[g];
    const int e1 = row_start[g + 1];

    float acc = 0.f;
    for (int eb = e0; eb < e1; eb += 32) {
        const int nloc = min(32, e1 - eb);
        const int p = (lane < nloc) ? payload[eb + lane] : 0;
        int k = 0;
        for (; k + 3 < nloc; k += 4) {
            const int s0 = __shfl(p, k,     32);
            const int s1 = __shfl(p, k + 1, 32);
            const int s2 = __shfl(p, k + 2, 32);
            const int s3 = __shfl(p, k + 3, 32);
            const float a = xw[(size_t)s0 * 32 + lane];
            const float b = xw[(size_t)s1 * 32 + lane];
            const float c = xw[(size_t)s2 * 32 + lane];
            const float d = xw[(size_t)s3 * 32 + lane];
            acc += a; acc += b; acc += c; acc += d;
        }
        for (; k < nloc; ++k)
            acc += xw[(size_t)__shfl(p, k, 32) * 32 + lane];
    }

    const float dg = fmaxf((float)(e1 - e0), 1.0f);
    const float v = fmaxf(acc / dg, 0.f);
    if (h_ws) h_ws[(size_t)g * 32 + lane] = v;
    out[(size_t)g * 96 + col_off + lane] = v;
    if (copy_x) out[(size_t)g * 96 + lane] = x[(size_t)g * 32 + lane];
}

// ---------------------------------------------------------------------------
// Fallback path kernels (small workspace): atomic scatter + finalize.
// ---------------------------------------------------------------------------
__global__ __launch_bounds__(256) void scatter_kernel(
    const int* __restrict__ src, const int* __restrict__ dst,
    const int* __restrict__ et,  const float* __restrict__ xw,
    float* __restrict__ acc, float* __restrict__ deg,
    int e_begin, int e_count, int r_begin, int with_deg)
{
    const int idx = blockIdx.x * 256 + threadIdx.x;
    if (idx >= e_count) return;
    const int e = e_begin + idx;
    const int s = src[e];
    const int d = dst[e];
    const int t = et[e] - r_begin;

    const float4* row = reinterpret_cast<const float4*>(xw + ((size_t)t * NN + s) * 32);
    float4 v[8];
#pragma unroll
    for (int k = 0; k < 8; ++k) v[k] = row[k];

    float* ap = acc + (size_t)d * 32;
#pragma unroll
    for (int k = 0; k < 8; ++k) {
        unsafeAtomicAdd(ap + 4 * k + 0, v[k].x);
        unsafeAtomicAdd(ap + 4 * k + 1, v[k].y);
        unsafeAtomicAdd(ap + 4 * k + 2, v[k].z);
        unsafeAtomicAdd(ap + 4 * k + 3, v[k].w);
    }
    if (with_deg) unsafeAtomicAdd(deg + d, 1.0f);
}

__global__ __launch_bounds__(256) void finalize_kernel(
    const float* __restrict__ x, const float* __restrict__ acc,
    const float* __restrict__ deg, float* __restrict__ h_ws,
    float* __restrict__ out, int col_off, int copy_x)
{
    const int i = blockIdx.x * 256 + threadIdx.x;
    if (i >= NN * 32) return;
    const int n = i >> 5, c = i & 31;
    const float dg = fmaxf(deg[n], 1.0f);
    float v = fmaxf(acc[i] / dg, 0.f);
    if (h_ws) h_ws[i] = v;
    out[(size_t)n * 96 + col_off + c] = v;
    if (copy_x) out[(size_t)n * 96 + c] = x[i];
}

__global__ __launch_bounds__(256) void xw_one_kernel(
    const float* __restrict__ x, const float* __restrict__ w,
    float* __restrict__ xw, int r)
{
    __shared__ float w_lds[1024];
    __shared__ float x_lds[32][32];
    const int base = blockIdx.x * 32;
    for (int i = threadIdx.x; i < 1024; i += 256)
        w_lds[i] = w[r * 1024 + i];
    for (int i = threadIdx.x; i < 1024; i += 256) {
        const int n = i >> 5, c = i & 31;
        const int nn = base + n;
        x_lds[n][c] = (nn < NN) ? x[(size_t)nn * 32 + c] : 0.f;
    }
    __syncthreads();
    const int j0 = threadIdx.x >> 5;
    const int o  = threadIdx.x & 31;
#pragma unroll
    for (int j = j0; j < 32; j += 8) {
        const int nn = base + j;
        if (nn >= NN) continue;
        float acc = 0.f;
#pragma unroll
        for (int i = 0; i < 32; ++i)
            acc += x_lds[j][i] * w_lds[i * 32 + o];
        xw[(size_t)nn * 32 + o] = acc;
    }
}

// ---------------------------------------------------------------------------
extern "C" void kernel_launch(void* const* d_in, const int* in_sizes, int n_in,
                              void* d_out, int out_size, void* d_ws, size_t ws_size,
                              hipStream_t stream)
{
    const float* x      = (const float*)d_in[0];
    const int*   ei     = (const int*)d_in[1];
    const int*   et     = (const int*)d_in[2];
    const float* basis0 = (const float*)d_in[4];
    const float* att0   = (const float*)d_in[5];
    const float* basis1 = (const float*)d_in[6];
    const float* att1   = (const float*)d_in[7];
    const int* src = ei;
    const int* dst = ei + EE;
    float* out = (float*)d_out;
    float* ws  = (float*)d_ws;

    const int nb256       = (NN + 255) / 256;      // 391
    const int node_blocks = (NN * 32 + 255) / 256; // 12500

    // ---- big path layout (4B units, keep xw 8B-aligned) ----
    float* w0         = ws;                                  // 8192
    float* w1         = w0 + 8192;                           // 8192
    int*   row_start  = (int*)(w1 + 8192);                   // NN+1
    int*   bucket_cnt = row_start + NN + 2;                  // NB   (+1 pad)
    int*   edge_base  = bucket_cnt + NB + 1;                 // NB+1 (+1 pad)
    int*   cursor     = edge_base + NB + 1;                  // NB
    int*   payload    = cursor + NB + 1;                     // EE   (+1 pad)
    float* h1         = (float*)(payload + EE);              // NN*32
    float* xw         = h1 + (size_t)NN * 32;                // RR*NN*32
    int2*  pairs      = (int2*)xw;   // scratch, only live before xw is written

    const size_t need_big =
        ((size_t)2 * 8192 + (NN + 2) + (NB + 1) + (NB + 1) + (NB + 1) + EE +
         (size_t)NN * 32 + (size_t)RR * NN * 32) * 4;

    if (ws_size >= need_big) {
        compute_w_kernel<<<16, 1024, 0, stream>>>(basis0, att0, basis1, att1, w0, w1);

        // ---- CSR build (once, reused by both layers) ----
        hipMemsetAsync(bucket_cnt, 0, (size_t)NB * 4, stream);
        bucket_hist_kernel<<<EB, 256, 0, stream>>>(dst, bucket_cnt);
        bucket_scan_kernel<<<1, 512, 0, stream>>>(bucket_cnt, edge_base, cursor);
        bucket_fill_kernel<<<EB, 256, 0, stream>>>(src, dst, cursor, pairs);
        bucket_sort_kernel<<<NB, 256, 0, stream>>>(pairs, edge_base, row_start, payload);

        // ---- layer 0 ----
        xw_reg_kernel<<<dim3(nb256, RR), 256, 0, stream>>>(x, w0, xw);
        gather_kernel<<<node_blocks, 256, 0, stream>>>(
            xw, row_start, payload, x, h1, out, 32, 1);

        // ---- layer 1 ----
        xw_reg_kernel<<<dim3(nb256, RR), 256, 0, stream>>>(h1, w1, xw);
        gather_kernel<<<node_blocks, 256, 0, stream>>>(
            xw, row_start, payload, x, nullptr, out, 64, 0);
        return;
    }

    // ---- fallback: small workspace, per-relation atomic scatter ----
    const int xw_blocks = (NN + 31) / 32;
    float* deg  = (float*)(w1 + 8192);            // NN
    float* acc  = deg + NN;                       // NN*32
    float* h1s  = acc + (size_t)NN * 32;          // NN*32
    float* xws  = h1s + (size_t)NN * 32;          // NN*32

    hipMemsetAsync(deg, 0, (size_t)(NN + (size_t)NN * 32) * 4, stream);
    compute_w_kernel<<<16, 1024, 0, stream>>>(basis0, att0, basis1, att1, w0, w1);

    for (int r = 0; r < RR; ++r) {
        xw_one_kernel<<<xw_blocks, 256, 0, stream>>>(x, w0, xws, r);
        scatter_kernel<<<(EPER + 255) / 256, 256, 0, stream>>>(
            src, dst, et, xws, acc, deg, r * EPER, EPER, r, 1);
    }
    finalize_kernel<<<node_blocks, 256, 0, stream>>>(x, acc, deg, h1s, out, 32, 1);

    hipMemsetAsync(acc, 0, (size_t)NN * 32 * 4, stream);
    for (int r = 0; r < RR; ++r) {
        xw_one_kernel<<<xw_blocks, 256, 0, stream>>>(h1s, w1, xws, r);
        scatter_kernel<<<(EPER + 255) / 256, 256, 0, stream>>>(
            src, dst, et, xws, acc, deg, r * EPER, EPER, r, 0);
    }
    finalize_kernel<<<node_blocks, 256, 0, stream>>>(x, acc, deg, nullptr, out, 64, 0);
}